// Round 2
// baseline (354.798 us; speedup 1.0000x reference)
//
#include <hip/hip_runtime.h>

#define Bb 4
#define Ss 2048
#define Hh 1024
#define Mm (Bb * Ss)   // 8192 rows
#define NC 32          // recurrence chunks
#define CL 64          // chunk length (NC*CL == Ss)

typedef short  s16x8 __attribute__((ext_vector_type(8)));
typedef float  f32x4 __attribute__((ext_vector_type(4)));

__device__ __forceinline__ float sigf(float z) { return 1.0f / (1.0f + __expf(-z)); }

// bf16 round-to-nearest-even helpers (bit-level, no API dependence)
__device__ __forceinline__ unsigned short f2bf(float x) {
    unsigned int u = __float_as_uint(x);
    u += 0x7FFFu + ((u >> 16) & 1u);
    return (unsigned short)(u >> 16);
}
__device__ __forceinline__ float bf2f(unsigned short h) {
    return __uint_as_float(((unsigned int)h) << 16);
}

// async global->LDS, 16B per lane (lane0-consistent pointers)
__device__ __forceinline__ void gl2lds16(const unsigned short* g, unsigned short* l) {
    __builtin_amdgcn_global_load_lds(
        (const __attribute__((address_space(1))) void*)g,
        (__attribute__((address_space(3))) void*)l,
        16, 0, 0);
}

// ---------------------------------------------------------------------------
// Split fp32 -> (bf16 hi, bf16 lo), 4 elems/thread
// ---------------------------------------------------------------------------
__global__ __launch_bounds__(256) void conv_split(
    const float* __restrict__ src, unsigned short* __restrict__ dh,
    unsigned short* __restrict__ dl, int n4)
{
    const int i = blockIdx.x * 256 + threadIdx.x;
    if (i >= n4) return;
    const float4 v = ((const float4*)src)[i];
    ushort4 h4, l4;
    const float vv[4] = {v.x, v.y, v.z, v.w};
    unsigned short* hp = (unsigned short*)&h4;
    unsigned short* lp = (unsigned short*)&l4;
    #pragma unroll
    for (int j = 0; j < 4; ++j) {
        const unsigned short hi = f2bf(vv[j]);
        hp[j] = hi;
        lp[j] = f2bf(vv[j] - bf2f(hi));
    }
    ((ushort4*)dh)[i] = h4;
    ((ushort4*)dl)[i] = l4;
}

// all 4 weights in one dispatch; dst row-block = blockIdx.y * H
// layout: rows 0-1023 Wi, 1024-2047 Wf, 2048-3071 Wg, 3072-4095 Wo
__global__ __launch_bounds__(256) void conv_w4(
    const float* __restrict__ W0, const float* __restrict__ W1,
    const float* __restrict__ W2, const float* __restrict__ W3,
    unsigned short* __restrict__ dh, unsigned short* __restrict__ dl)
{
    const int which = blockIdx.y;
    const float* src = (which == 0) ? W0 : (which == 1) ? W1 : (which == 2) ? W2 : W3;
    const int i = blockIdx.x * 256 + threadIdx.x;          // 0 .. HH/4-1
    const size_t o = (size_t)which * ((size_t)Hh * Hh / 4) + i;
    const float4 v = ((const float4*)src)[i];
    ushort4 h4, l4;
    const float vv[4] = {v.x, v.y, v.z, v.w};
    unsigned short* hp = (unsigned short*)&h4;
    unsigned short* lp = (unsigned short*)&l4;
    #pragma unroll
    for (int j = 0; j < 4; ++j) {
        const unsigned short hi = f2bf(vv[j]);
        hp[j] = hi;
        lp[j] = f2bf(vv[j] - bf2f(hi));
    }
    ((ushort4*)dh)[o] = h4;
    ((ushort4*)dl)[o] = l4;
}

// ---------------------------------------------------------------------------
// Split-bf16 MFMA GEMM: C[M, N] = A[M,K=1024] @ B[N,K]^T, raw store.
// acc = Ah*Bh + Al*Bh + Ah*Bl (fp32 MFMA accumulate).
//
// Single-barrier deep pipeline (R2):
//   tile 128x256, BK=32, 8 waves (2M x 4N, each 64x64 out).
//   ring-3 LDS (3 x 48KB, fragment-major, conflict-free, global_load_lds-legal):
//   step t computes buf[t%3], stages buf[(t+2)%3].
//   ONE barrier per K-step (after counted vmcnt(6)) — ring-3 makes mid-phase
//   barriers unnecessary for correctness: a wave reaching the end barrier has
//   consumed all its ds_reads (MFMAs depend on them), and staging targets a
//   buffer idle for 2 steps. Waves drift within the interval -> ds_read of one
//   wave overlaps MFMA of another; compiler's incremental lgkmcnt overlaps a
//   wave's own reads with its early MFMAs.
//   T1: bijective XCD swizzle (nwg % 8 == 0 at both call sites).
// Columns n < nsplit -> C0 (ld0); n >= nsplit -> C1 at col n-nsplit (ld1).
// ---------------------------------------------------------------------------

#define RD_A(j) { ah[j] = *(const s16x8*)(cb +          (wr4 + (j)) * 512 + lo); \
                  al[j] = *(const s16x8*)(cb +  4096 + (wr4 + (j)) * 512 + lo); }
#define RD_B(j) { bh[j] = *(const s16x8*)(cb +  8192 + (wc4 + (j)) * 512 + lo); \
                  bl[j] = *(const s16x8*)(cb + 16384 + (wc4 + (j)) * 512 + lo); }
#define MM(mi, ni) { \
    acc[mi][ni] = __builtin_amdgcn_mfma_f32_16x16x32_bf16(ah[mi], bh[ni], acc[mi][ni], 0, 0, 0); \
    acc[mi][ni] = __builtin_amdgcn_mfma_f32_16x16x32_bf16(al[mi], bh[ni], acc[mi][ni], 0, 0, 0); \
    acc[mi][ni] = __builtin_amdgcn_mfma_f32_16x16x32_bf16(ah[mi], bl[ni], acc[mi][ni], 0, 0, 0); }

// one K-step: stage 6 blocks for t+2, read all 16 fragments, 48 MFMA
#define KSTEP1(cbP, sbP, kn, STG) do { \
    const unsigned short* cb = (cbP); \
    if (STG) { \
        gl2lds16(gp[0] + (kn), (sbP) + lb[0] + lo); \
        gl2lds16(gp[1] + (kn), (sbP) + lb[1] + lo); \
        gl2lds16(gp[2] + (kn), (sbP) + lb[2] + lo); \
        gl2lds16(gp[3] + (kn), (sbP) + lb[3] + lo); \
        gl2lds16(gp[4] + (kn), (sbP) + lb[4] + lo); \
        gl2lds16(gp[5] + (kn), (sbP) + lb[5] + lo); \
    } \
    RD_A(0) RD_B(0) RD_B(1) RD_A(1) \
    RD_B(2) RD_B(3) RD_A(2) RD_A(3) \
    __builtin_amdgcn_s_setprio(1); \
    MM(0,0) MM(0,1) MM(0,2) MM(0,3) \
    MM(1,0) MM(1,1) MM(1,2) MM(1,3) \
    MM(2,0) MM(2,1) MM(2,2) MM(2,3) \
    MM(3,0) MM(3,1) MM(3,2) MM(3,3) \
    __builtin_amdgcn_s_setprio(0); \
} while (0)

__global__ __launch_bounds__(512, 2) void gemm_split(
    const unsigned short* __restrict__ Ah, const unsigned short* __restrict__ Al,
    const unsigned short* __restrict__ Bh, const unsigned short* __restrict__ Bl,
    float* __restrict__ C0, int ld0, float* __restrict__ C1, int ld1, int nsplit)
{
    // per buffer (shorts): A_h [0,4096) A_l [4096,8192) B_h [8192,16384) B_l [16384,24576)
    __shared__ __align__(16) unsigned short lds[3][24576];   // 144 KiB

    const int tid  = threadIdx.x;
    const int lane = tid & 63;
    const int wave = tid >> 6;           // 0..7
    const int wr4  = (wave >> 2) * 4;    // M-half fragment base
    const int wc4  = (wave & 3) * 4;     // N-quarter fragment base
    const int lm   = lane & 15;
    const int kq   = lane >> 4;
    const int lo   = lane * 8;           // lane's 16B slot (shorts)

    // T1: bijective XCD-aware swizzle (nwg % 8 == 0 at both call sites)
    const int nwg = gridDim.x * gridDim.y;
    const int bid = blockIdx.y * gridDim.x + blockIdx.x;
    const int swz = (bid & 7) * (nwg >> 3) + (bid >> 3);
    const int m0  = (swz / gridDim.x) * 128;
    const int n0  = (swz % gridDim.x) * 256;

    // stage assignment: 48 x 1KiB fragment-blocks per buffer; wave w owns blocks
    // w*6 .. w*6+5. Block ids: 0-7 A_h, 8-15 A_l, 16-31 B_h, 32-47 B_l.
    const unsigned short* gp[6];
    int lb[6];
    #pragma unroll
    for (int i = 0; i < 6; ++i) {
        const int blk = wave * 6 + i;
        lb[i] = blk * 512;
        const unsigned short* base; int row;
        if (blk < 8)       { base = Ah; row = m0 + blk * 16; }
        else if (blk < 16) { base = Al; row = m0 + (blk - 8) * 16; }
        else if (blk < 32) { base = Bh; row = n0 + (blk - 16) * 16; }
        else               { base = Bl; row = n0 + (blk - 32) * 16; }
        gp[i] = base + (size_t)(row + lm) * Hh + kq * 8;
    }

    f32x4 acc[4][4] = {};
    s16x8 ah[4], al[4], bh[4], bl[4];

    unsigned short* b0 = &lds[0][0];
    unsigned short* b1 = &lds[1][0];
    unsigned short* b2 = &lds[2][0];

    // prologue: stage K-step 0 -> buf0, K-step 1 -> buf1; need only buf0 done
    #pragma unroll
    for (int i = 0; i < 6; ++i) gl2lds16(gp[i],      b0 + lb[i] + lo);
    #pragma unroll
    for (int i = 0; i < 6; ++i) gl2lds16(gp[i] + 32, b1 + lb[i] + lo);
    asm volatile("s_waitcnt vmcnt(6)" ::: "memory");
    __builtin_amdgcn_s_barrier();

    // main loop: step t computes b0, stages t+2 into b2; ONE barrier per step.
    // vmcnt(6) = let this step's 6 staging loads fly, require last step's done.
    #pragma unroll 1
    for (int t = 0; t < 30; ++t) {
        KSTEP1(b0, b2, (t + 2) * 32, true);
        asm volatile("s_waitcnt vmcnt(6)" ::: "memory");
        __builtin_amdgcn_s_barrier();
        unsigned short* tmp = b0; b0 = b1; b1 = b2; b2 = tmp;
    }
    // peeled tail: steps 30, 31 (no staging)
    KSTEP1(b0, b2, 0, false);
    asm volatile("s_waitcnt vmcnt(0)" ::: "memory");
    __builtin_amdgcn_s_barrier();
    KSTEP1(b1, b2, 0, false);

    // epilogue: D[row = kq*4 + r][col = lm] per 16x16 tile
    #pragma unroll
    for (int mi = 0; mi < 4; ++mi)
        #pragma unroll
        for (int ni = 0; ni < 4; ++ni) {
            const int n = n0 + (wc4 >> 2) * 64 + ni * 16 + lm;
            const bool sec = (n >= nsplit);
            float* Cp  = sec ? C1 : C0;
            const int ld = sec ? ld1 : ld0;
            const int nn = sec ? n - nsplit : n;
            #pragma unroll
            for (int r = 0; r < 4; ++r) {
                const int m = m0 + (wr4 >> 2) * 64 + mi * 16 + kq * 4 + r;
                Cp[(size_t)m * ld + nn] = acc[mi][ni][r];
            }
        }
}

// ---------------------------------------------------------------------------
// Recurrence pass 1: per (b,h,chunk) compute P = prod(f), L = local final h
// reads raw z_i,z_f from zif[M,2048] (cols 0-1023 z_i, 1024-2047 z_f)
// ---------------------------------------------------------------------------
__global__ __launch_bounds__(256) void scan1(
    const float* __restrict__ zif, float2* __restrict__ csum)
{
    const int g  = blockIdx.x * 256 + threadIdx.x;  // 0..131071
    const int c  = g >> 12;                          // chunk 0..31
    const int bh = g & 4095;
    const int b  = bh >> 10, h = bh & 1023;
    const size_t base = (size_t)b * Ss * 2048 + h;
    const int s0 = c * CL;
    float P = 1.0f, L = 0.0f;
    for (int j = 0; j < CL; j += 4) {
        float zi[4], zf[4];
        #pragma unroll
        for (int q = 0; q < 4; ++q) {
            const size_t off = base + (size_t)(s0 + j + q) * 2048;
            zi[q] = zif[off]; zf[q] = zif[off + 1024];
        }
        #pragma unroll
        for (int q = 0; q < 4; ++q) {
            const float f  = sigf(zf[q]);
            const float ip = zi[q] * sigf(zi[q]) * (1.0f - f);
            L = fmaf(f, L, ip); P *= f;
        }
    }
    csum[(size_t)bh * NC + c] = make_float2(P, L);
}

// ---------------------------------------------------------------------------
// Recurrence pass 2: combine chunk prefixes, replay chunk, emit gh as bf16 hi/lo
// ---------------------------------------------------------------------------
__global__ __launch_bounds__(256) void scan2(
    const float* __restrict__ zif, const float* __restrict__ zg,
    const float2* __restrict__ csum,
    unsigned short* __restrict__ ghh, unsigned short* __restrict__ ghl)
{
    const int g  = blockIdx.x * 256 + threadIdx.x;
    const int c  = g >> 12;
    const int bh = g & 4095;
    const int b  = bh >> 10, h = bh & 1023;
    const size_t base  = (size_t)b * Ss * 2048 + h;   // zif
    const size_t baseg = (size_t)b * Ss * 1024 + h;   // zg / gh
    float hh = 0.0f;
    for (int cp = 0; cp < c; ++cp) {
        const float2 pl = csum[(size_t)bh * NC + cp];
        hh = fmaf(pl.x, hh, pl.y);
    }
    const int s0 = c * CL;
    for (int j = 0; j < CL; j += 4) {
        float zi[4], zf[4], gv[4];
        #pragma unroll
        for (int q = 0; q < 4; ++q) {
            const size_t off = base + (size_t)(s0 + j + q) * 2048;
            zi[q] = zif[off]; zf[q] = zif[off + 1024];
            gv[q] = zg[baseg + (size_t)(s0 + j + q) * 1024];
        }
        #pragma unroll
        for (int q = 0; q < 4; ++q) {
            const float f  = sigf(zf[q]);
            const float ip = zi[q] * sigf(zi[q]) * (1.0f - f);
            hh = fmaf(f, hh, ip);
            const float gh = gv[q] * hh;
            const unsigned short hi = f2bf(gh);
            const size_t off = baseg + (size_t)(s0 + j + q) * 1024;
            ghh[off] = hi;
            ghl[off] = f2bf(gh - bf2f(hi));
        }
    }
}

// ===========================================================================
// Round-1 fp32 fallback (only if ws_size is too small for the split path)
// ===========================================================================
__global__ __launch_bounds__(256) void proj_kernel(
    const float* __restrict__ x,  const float* __restrict__ Wi,
    const float* __restrict__ Wf, const float* __restrict__ Wg,
    float* __restrict__ f_out, float* __restrict__ inp_out, float* __restrict__ g_out)
{
    __shared__ __align__(16) float As [16][68];
    __shared__ __align__(16) float Bis[16][68];
    __shared__ __align__(16) float Bfs[16][68];
    __shared__ __align__(16) float Bgs[16][68];
    const int tid = threadIdx.x;
    const int tx = tid & 15, ty = tid >> 4;
    const int m0 = blockIdx.x * 64, n0 = blockIdx.y * 64;
    const int lr = tid >> 2, lk = (tid & 3) << 2;
    float acc_i[4][4] = {}, acc_f[4][4] = {}, acc_g[4][4] = {};
    const float* pA = x  + (size_t)(m0 + lr) * Hh + lk;
    const float* pI = Wi + (size_t)(n0 + lr) * Hh + lk;
    const float* pF = Wf + (size_t)(n0 + lr) * Hh + lk;
    const float* pG = Wg + (size_t)(n0 + lr) * Hh + lk;
    for (int k0 = 0; k0 < Hh; k0 += 16) {
        const float4 av = *(const float4*)(pA + k0);
        const float4 iv = *(const float4*)(pI + k0);
        const float4 fv = *(const float4*)(pF + k0);
        const float4 gv = *(const float4*)(pG + k0);
        __syncthreads();
        As [lk+0][lr] = av.x; As [lk+1][lr] = av.y; As [lk+2][lr] = av.z; As [lk+3][lr] = av.w;
        Bis[lk+0][lr] = iv.x; Bis[lk+1][lr] = iv.y; Bis[lk+2][lr] = iv.z; Bis[lk+3][lr] = iv.w;
        Bfs[lk+0][lr] = fv.x; Bfs[lk+1][lr] = fv.y; Bfs[lk+2][lr] = fv.z; Bfs[lk+3][lr] = fv.w;
        Bgs[lk+0][lr] = gv.x; Bgs[lk+1][lr] = gv.y; Bgs[lk+2][lr] = gv.z; Bgs[lk+3][lr] = gv.w;
        __syncthreads();
        #pragma unroll
        for (int kk = 0; kk < 16; ++kk) {
            const float4 a  = *(const float4*)&As [kk][ty << 2];
            const float4 bi = *(const float4*)&Bis[kk][tx << 2];
            const float4 bf = *(const float4*)&Bfs[kk][tx << 2];
            const float4 bg = *(const float4*)&Bgs[kk][tx << 2];
            const float aa[4]  = {a.x,a.y,a.z,a.w};
            const float bbi[4] = {bi.x,bi.y,bi.z,bi.w};
            const float bbf[4] = {bf.x,bf.y,bf.z,bf.w};
            const float bbg[4] = {bg.x,bg.y,bg.z,bg.w};
            #pragma unroll
            for (int i = 0; i < 4; ++i)
                #pragma unroll
                for (int j = 0; j < 4; ++j) {
                    acc_i[i][j] = fmaf(aa[i], bbi[j], acc_i[i][j]);
                    acc_f[i][j] = fmaf(aa[i], bbf[j], acc_f[i][j]);
                    acc_g[i][j] = fmaf(aa[i], bbg[j], acc_g[i][j]);
                }
        }
    }
    #pragma unroll
    for (int i = 0; i < 4; ++i) {
        const size_t row = (size_t)(m0 + (ty << 2) + i) * Hh + n0 + (tx << 2);
        float4 vf, vp, vg;
        float* qf = (float*)&vf; float* qp = (float*)&vp; float* qg = (float*)&vg;
        #pragma unroll
        for (int j = 0; j < 4; ++j) {
            const float ff = sigf(acc_f[i][j]);
            const float zi = acc_i[i][j];
            qf[j] = ff; qp[j] = zi * sigf(zi) * (1.0f - ff); qg[j] = acc_g[i][j];
        }
        *(float4*)(f_out + row) = vf;
        *(float4*)(inp_out + row) = vp;
        *(float4*)(g_out + row) = vg;
    }
}

__global__ __launch_bounds__(256) void recur_kernel(
    const float* f_buf, const float* __restrict__ inp_buf,
    const float* __restrict__ g_buf, float* gh_out)
{
    const int t = blockIdx.x * 256 + threadIdx.x;
    const int b = t >> 10, h = t & 1023;
    const size_t base = (size_t)b * Ss * Hh + h;
    float hh = 0.0f;
    for (int s0 = 0; s0 < Ss; s0 += 8) {
        float fr[8], ir[8], gr[8], o[8];
        #pragma unroll
        for (int j = 0; j < 8; ++j) {
            const size_t off = base + (size_t)(s0 + j) * Hh;
            fr[j] = f_buf[off]; ir[j] = inp_buf[off]; gr[j] = g_buf[off];
        }
        #pragma unroll
        for (int j = 0; j < 8; ++j) { hh = fmaf(fr[j], hh, ir[j]); o[j] = gr[j] * hh; }
        #pragma unroll
        for (int j = 0; j < 8; ++j) gh_out[base + (size_t)(s0 + j) * Hh] = o[j];
    }
}

__global__ __launch_bounds__(256) void out_kernel(
    const float* __restrict__ A, const float* __restrict__ Wo, float* __restrict__ out)
{
    __shared__ __align__(16) float As[16][68];
    __shared__ __align__(16) float Bs[16][68];
    const int tid = threadIdx.x;
    const int tx = tid & 15, ty = tid >> 4;
    const int m0 = blockIdx.x * 64, n0 = blockIdx.y * 64;
    const int lr = tid >> 2, lk = (tid & 3) << 2;
    float acc[4][4] = {};
    const float* pA = A  + (size_t)(m0 + lr) * Hh + lk;
    const float* pB = Wo + (size_t)(n0 + lr) * Hh + lk;
    for (int k0 = 0; k0 < Hh; k0 += 16) {
        const float4 av = *(const float4*)(pA + k0);
        const float4 bv = *(const float4*)(pB + k0);
        __syncthreads();
        As[lk+0][lr] = av.x; As[lk+1][lr] = av.y; As[lk+2][lr] = av.z; As[lk+3][lr] = av.w;
        Bs[lk+0][lr] = bv.x; Bs[lk+1][lr] = bv.y; Bs[lk+2][lr] = bv.z; Bs[lk+3][lr] = bv.w;
        __syncthreads();
        #pragma unroll
        for (int kk = 0; kk < 16; ++kk) {
            const float4 a = *(const float4*)&As[kk][ty << 2];
            const float4 b = *(const float4*)&Bs[kk][tx << 2];
            const float aa[4] = {a.x,a.y,a.z,a.w};
            const float bb[4] = {b.x,b.y,b.z,b.w};
            #pragma unroll
            for (int i = 0; i < 4; ++i)
                #pragma unroll
                for (int j = 0; j < 4; ++j)
                    acc[i][j] = fmaf(aa[i], bb[j], acc[i][j]);
        }
    }
    #pragma unroll
    for (int i = 0; i < 4; ++i) {
        const size_t row = (size_t)(m0 + (ty << 2) + i) * Hh + n0 + (tx << 2);
        float4 v;
        ((float*)&v)[0]=acc[i][0]; ((float*)&v)[1]=acc[i][1];
        ((float*)&v)[2]=acc[i][2]; ((float*)&v)[3]=acc[i][3];
        *(float4*)(out + row) = v;
    }
}

extern "C" void kernel_launch(void* const* d_in, const int* in_sizes, int n_in,
                              void* d_out, int out_size, void* d_ws, size_t ws_size,
                              hipStream_t stream) {
    const float* x  = (const float*)d_in[0];
    const float* Wi = (const float*)d_in[1];
    const float* Wf = (const float*)d_in[2];
    const float* Wg = (const float*)d_in[3];
    const float* Wo = (const float*)d_in[4];
    float* out = (float*)d_out;

    const size_t MH = (size_t)Mm * Hh;      // 8388608
    const size_t HH = (size_t)Hh * Hh;      // 1048576

    // ws layout (split path), ~152 MB:
    // xh[MH], xl[MH], Wallh[4HH], Walll[4HH] (rows: Wi,Wf,Wg,Wo),
    // zif[M*2048]f32, ghh[MH], ghl[MH], csum[4096*NC]float2
    size_t need = MH*2*2 + HH*4*2*2 + MH*2*4 + MH*2*2 + (size_t)4096*NC*8;

    if (ws_size >= need) {
        char* p = (char*)d_ws;
        unsigned short* xh    = (unsigned short*)p;  p += MH*2;
        unsigned short* xl    = (unsigned short*)p;  p += MH*2;
        unsigned short* Wallh = (unsigned short*)p;  p += HH*4*2;
        unsigned short* Walll = (unsigned short*)p;  p += HH*4*2;
        float* zif            = (float*)p;           p += MH*2*4;
        unsigned short* ghh   = (unsigned short*)p;  p += MH*2;
        unsigned short* ghl   = (unsigned short*)p;  p += MH*2;
        float2* csum          = (float2*)p;

        conv_split<<<(int)(MH/4/256), 256, 0, stream>>>(x, xh, xl, (int)(MH/4));
        conv_w4<<<dim3((unsigned)(HH/4/256/1), 4), 256, 0, stream>>>(Wi, Wf, Wg, Wo, Wallh, Walll);

        // fused projections: N=3072 (Wi|Wf|Wg); cols <2048 -> zif, >=2048 (z_g) -> d_out
        // tile 128x256: grid (3072/256, 8192/128)
        gemm_split<<<dim3(12, 64), 512, 0, stream>>>(
            xh, xl, Wallh, Walll, zif, 2048, out, 1024, 2048);

        scan1<<<512, 256, 0, stream>>>(zif, csum);
        scan2<<<512, 256, 0, stream>>>(zif, out, csum, ghh, ghl);

        // out = gh @ Wo^T  (Wo rows live at offset 3*HH in the concat)
        gemm_split<<<dim3(4, 64), 512, 0, stream>>>(
            ghh, ghl, Wallh + 3*HH, Walll + 3*HH, out, 1024, out, 1024, 1 << 30);
    } else {
        float* f_buf   = (float*)d_ws;
        float* inp_buf = f_buf + MH;
        dim3 grid(Mm / 64, Hh / 64);
        proj_kernel<<<grid, 256, 0, stream>>>(x, Wi, Wf, Wg, f_buf, inp_buf, out);
        recur_kernel<<<16, 256, 0, stream>>>(f_buf, inp_buf, out, f_buf);
        out_kernel<<<grid, 256, 0, stream>>>(f_buf, Wo, out);
    }
}

// Round 3
// 344.292 us; speedup vs baseline: 1.0305x; 1.0305x over previous
//
#include <hip/hip_runtime.h>

#define Bb 4
#define Ss 2048
#define Hh 1024
#define Mm (Bb * Ss)   // 8192 rows
#define NC 32          // recurrence chunks
#define CL 64          // chunk length (NC*CL == Ss)

typedef short  s16x8 __attribute__((ext_vector_type(8)));
typedef float  f32x4 __attribute__((ext_vector_type(4)));

__device__ __forceinline__ float sigf(float z) { return 1.0f / (1.0f + __expf(-z)); }

// bf16 round-to-nearest-even helpers (bit-level, no API dependence)
__device__ __forceinline__ unsigned short f2bf(float x) {
    unsigned int u = __float_as_uint(x);
    u += 0x7FFFu + ((u >> 16) & 1u);
    return (unsigned short)(u >> 16);
}
__device__ __forceinline__ float bf2f(unsigned short h) {
    return __uint_as_float(((unsigned int)h) << 16);
}

// async global->LDS, 16B per lane (lane0-consistent pointers)
__device__ __forceinline__ void gl2lds16(const unsigned short* g, unsigned short* l) {
    __builtin_amdgcn_global_load_lds(
        (const __attribute__((address_space(1))) void*)g,
        (__attribute__((address_space(3))) void*)l,
        16, 0, 0);
}

// ---------------------------------------------------------------------------
// Split fp32 -> (bf16 hi, bf16 lo), 4 elems/thread
// ---------------------------------------------------------------------------
__global__ __launch_bounds__(256) void conv_split(
    const float* __restrict__ src, unsigned short* __restrict__ dh,
    unsigned short* __restrict__ dl, int n4)
{
    const int i = blockIdx.x * 256 + threadIdx.x;
    if (i >= n4) return;
    const float4 v = ((const float4*)src)[i];
    ushort4 h4, l4;
    const float vv[4] = {v.x, v.y, v.z, v.w};
    unsigned short* hp = (unsigned short*)&h4;
    unsigned short* lp = (unsigned short*)&l4;
    #pragma unroll
    for (int j = 0; j < 4; ++j) {
        const unsigned short hi = f2bf(vv[j]);
        hp[j] = hi;
        lp[j] = f2bf(vv[j] - bf2f(hi));
    }
    ((ushort4*)dh)[i] = h4;
    ((ushort4*)dl)[i] = l4;
}

// all 4 weights in one dispatch; dst row-block = blockIdx.y * H
// layout: rows 0-1023 Wi, 1024-2047 Wf, 2048-3071 Wg, 3072-4095 Wo
__global__ __launch_bounds__(256) void conv_w4(
    const float* __restrict__ W0, const float* __restrict__ W1,
    const float* __restrict__ W2, const float* __restrict__ W3,
    unsigned short* __restrict__ dh, unsigned short* __restrict__ dl)
{
    const int which = blockIdx.y;
    const float* src = (which == 0) ? W0 : (which == 1) ? W1 : (which == 2) ? W2 : W3;
    const int i = blockIdx.x * 256 + threadIdx.x;          // 0 .. HH/4-1
    const size_t o = (size_t)which * ((size_t)Hh * Hh / 4) + i;
    const float4 v = ((const float4*)src)[i];
    ushort4 h4, l4;
    const float vv[4] = {v.x, v.y, v.z, v.w};
    unsigned short* hp = (unsigned short*)&h4;
    unsigned short* lp = (unsigned short*)&l4;
    #pragma unroll
    for (int j = 0; j < 4; ++j) {
        const unsigned short hi = f2bf(vv[j]);
        hp[j] = hi;
        lp[j] = f2bf(vv[j] - bf2f(hi));
    }
    ((ushort4*)dh)[o] = h4;
    ((ushort4*)dl)[o] = l4;
}

// ---------------------------------------------------------------------------
// Split-bf16 MFMA GEMM: C[M, N] = A[M,K=1024] @ B[N,K]^T, raw store.
// acc = Ah*Bh + Al*Bh + Ah*Bl (fp32 MFMA accumulate).
//
// R3: term-major MFMA order. The split algorithm's natural per-element form
// acc = mfma(ah,bl, mfma(al,bh, mfma(ah,bh, acc))) issues 3 serially
// DEPENDENT MFMAs back-to-back -> matrix pipe stalls on dep latency every
// triple (the schedule-invariant ~37% MfmaUtil across R1/R2). Term-major
// order (all 16 Ah*Bh, then 16 Al*Bh, then 16 Ah*Bl) keeps per-acc-element
// operation order IDENTICAL (hh,lh,hl — bit-exact) but puts dependent MFMAs
// 16 instructions apart.
//
//   tile 128x256, BK=32, 8 waves (2M x 4N, each 64x64 out).
//   ring-3 LDS (3 x 48KB, fragment-major, conflict-free, global_load_lds-legal):
//   step t computes buf[t%3], stages buf[(t+2)%3]. ONE barrier per K-step
//   after counted vmcnt(6). T1: bijective XCD swizzle (nwg % 8 == 0).
// Columns n < nsplit -> C0 (ld0); n >= nsplit -> C1 at col n-nsplit (ld1).
// ---------------------------------------------------------------------------

#define RD_A(j) { ah[j] = *(const s16x8*)(cb +          (wr4 + (j)) * 512 + lo); \
                  al[j] = *(const s16x8*)(cb +  4096 + (wr4 + (j)) * 512 + lo); }
#define RD_B(j) { bh[j] = *(const s16x8*)(cb +  8192 + (wc4 + (j)) * 512 + lo); \
                  bl[j] = *(const s16x8*)(cb + 16384 + (wc4 + (j)) * 512 + lo); }

#define MM_HH(mi, ni) acc[mi][ni] = __builtin_amdgcn_mfma_f32_16x16x32_bf16(ah[mi], bh[ni], acc[mi][ni], 0, 0, 0);
#define MM_LH(mi, ni) acc[mi][ni] = __builtin_amdgcn_mfma_f32_16x16x32_bf16(al[mi], bh[ni], acc[mi][ni], 0, 0, 0);
#define MM_HL(mi, ni) acc[mi][ni] = __builtin_amdgcn_mfma_f32_16x16x32_bf16(ah[mi], bl[ni], acc[mi][ni], 0, 0, 0);

// one K-step: stage 6 blocks for t+2, read all 16 fragments, 48 MFMA term-major
#define KSTEP1(cbP, sbP, kn, STG) do { \
    const unsigned short* cb = (cbP); \
    if (STG) { \
        gl2lds16(gp[0] + (kn), (sbP) + lb[0] + lo); \
        gl2lds16(gp[1] + (kn), (sbP) + lb[1] + lo); \
        gl2lds16(gp[2] + (kn), (sbP) + lb[2] + lo); \
        gl2lds16(gp[3] + (kn), (sbP) + lb[3] + lo); \
        gl2lds16(gp[4] + (kn), (sbP) + lb[4] + lo); \
        gl2lds16(gp[5] + (kn), (sbP) + lb[5] + lo); \
    } \
    RD_A(0) RD_B(0) RD_A(1) RD_B(1) \
    RD_A(2) RD_B(2) RD_A(3) RD_B(3) \
    __builtin_amdgcn_s_setprio(1); \
    MM_HH(0,0) MM_HH(0,1) MM_HH(0,2) MM_HH(0,3) \
    MM_HH(1,0) MM_HH(1,1) MM_HH(1,2) MM_HH(1,3) \
    MM_HH(2,0) MM_HH(2,1) MM_HH(2,2) MM_HH(2,3) \
    MM_HH(3,0) MM_HH(3,1) MM_HH(3,2) MM_HH(3,3) \
    MM_LH(0,0) MM_LH(0,1) MM_LH(0,2) MM_LH(0,3) \
    MM_LH(1,0) MM_LH(1,1) MM_LH(1,2) MM_LH(1,3) \
    MM_LH(2,0) MM_LH(2,1) MM_LH(2,2) MM_LH(2,3) \
    MM_LH(3,0) MM_LH(3,1) MM_LH(3,2) MM_LH(3,3) \
    MM_HL(0,0) MM_HL(0,1) MM_HL(0,2) MM_HL(0,3) \
    MM_HL(1,0) MM_HL(1,1) MM_HL(1,2) MM_HL(1,3) \
    MM_HL(2,0) MM_HL(2,1) MM_HL(2,2) MM_HL(2,3) \
    MM_HL(3,0) MM_HL(3,1) MM_HL(3,2) MM_HL(3,3) \
    __builtin_amdgcn_s_setprio(0); \
} while (0)

__global__ __launch_bounds__(512, 2) void gemm_split(
    const unsigned short* __restrict__ Ah, const unsigned short* __restrict__ Al,
    const unsigned short* __restrict__ Bh, const unsigned short* __restrict__ Bl,
    float* __restrict__ C0, int ld0, float* __restrict__ C1, int ld1, int nsplit)
{
    // per buffer (shorts): A_h [0,4096) A_l [4096,8192) B_h [8192,16384) B_l [16384,24576)
    __shared__ __align__(16) unsigned short lds[3][24576];   // 144 KiB

    const int tid  = threadIdx.x;
    const int lane = tid & 63;
    const int wave = tid >> 6;           // 0..7
    const int wr4  = (wave >> 2) * 4;    // M-half fragment base
    const int wc4  = (wave & 3) * 4;     // N-quarter fragment base
    const int lm   = lane & 15;
    const int kq   = lane >> 4;
    const int lo   = lane * 8;           // lane's 16B slot (shorts)

    // T1: bijective XCD-aware swizzle (nwg % 8 == 0 at both call sites)
    const int nwg = gridDim.x * gridDim.y;
    const int bid = blockIdx.y * gridDim.x + blockIdx.x;
    const int swz = (bid & 7) * (nwg >> 3) + (bid >> 3);
    const int m0  = (swz / gridDim.x) * 128;
    const int n0  = (swz % gridDim.x) * 256;

    // stage assignment: 48 x 1KiB fragment-blocks per buffer; wave w owns blocks
    // w*6 .. w*6+5. Block ids: 0-7 A_h, 8-15 A_l, 16-31 B_h, 32-47 B_l.
    const unsigned short* gp[6];
    int lb[6];
    #pragma unroll
    for (int i = 0; i < 6; ++i) {
        const int blk = wave * 6 + i;
        lb[i] = blk * 512;
        const unsigned short* base; int row;
        if (blk < 8)       { base = Ah; row = m0 + blk * 16; }
        else if (blk < 16) { base = Al; row = m0 + (blk - 8) * 16; }
        else if (blk < 32) { base = Bh; row = n0 + (blk - 16) * 16; }
        else               { base = Bl; row = n0 + (blk - 32) * 16; }
        gp[i] = base + (size_t)(row + lm) * Hh + kq * 8;
    }

    f32x4 acc[4][4] = {};
    s16x8 ah[4], al[4], bh[4], bl[4];

    unsigned short* b0 = &lds[0][0];
    unsigned short* b1 = &lds[1][0];
    unsigned short* b2 = &lds[2][0];

    // prologue: stage K-step 0 -> buf0, K-step 1 -> buf1; need only buf0 done
    #pragma unroll
    for (int i = 0; i < 6; ++i) gl2lds16(gp[i],      b0 + lb[i] + lo);
    #pragma unroll
    for (int i = 0; i < 6; ++i) gl2lds16(gp[i] + 32, b1 + lb[i] + lo);
    asm volatile("s_waitcnt vmcnt(6)" ::: "memory");
    __builtin_amdgcn_s_barrier();

    // main loop: step t computes b0, stages t+2 into b2; ONE barrier per step.
    // vmcnt(6) = let this step's 6 staging loads fly, require last step's done.
    #pragma unroll 1
    for (int t = 0; t < 30; ++t) {
        KSTEP1(b0, b2, (t + 2) * 32, true);
        asm volatile("s_waitcnt vmcnt(6)" ::: "memory");
        __builtin_amdgcn_s_barrier();
        unsigned short* tmp = b0; b0 = b1; b1 = b2; b2 = tmp;
    }
    // peeled tail: steps 30, 31 (no staging)
    KSTEP1(b0, b2, 0, false);
    asm volatile("s_waitcnt vmcnt(0)" ::: "memory");
    __builtin_amdgcn_s_barrier();
    KSTEP1(b1, b2, 0, false);

    // epilogue: D[row = kq*4 + r][col = lm] per 16x16 tile
    #pragma unroll
    for (int mi = 0; mi < 4; ++mi)
        #pragma unroll
        for (int ni = 0; ni < 4; ++ni) {
            const int n = n0 + (wc4 >> 2) * 64 + ni * 16 + lm;
            const bool sec = (n >= nsplit);
            float* Cp  = sec ? C1 : C0;
            const int ld = sec ? ld1 : ld0;
            const int nn = sec ? n - nsplit : n;
            #pragma unroll
            for (int r = 0; r < 4; ++r) {
                const int m = m0 + (wr4 >> 2) * 64 + mi * 16 + kq * 4 + r;
                Cp[(size_t)m * ld + nn] = acc[mi][ni][r];
            }
        }
}

// ---------------------------------------------------------------------------
// Recurrence pass 1: per (b,h,chunk) compute P = prod(f), L = local final h
// reads raw z_i,z_f from zif[M,2048] (cols 0-1023 z_i, 1024-2047 z_f)
// ---------------------------------------------------------------------------
__global__ __launch_bounds__(256) void scan1(
    const float* __restrict__ zif, float2* __restrict__ csum)
{
    const int g  = blockIdx.x * 256 + threadIdx.x;  // 0..131071
    const int c  = g >> 12;                          // chunk 0..31
    const int bh = g & 4095;
    const int b  = bh >> 10, h = bh & 1023;
    const size_t base = (size_t)b * Ss * 2048 + h;
    const int s0 = c * CL;
    float P = 1.0f, L = 0.0f;
    for (int j = 0; j < CL; j += 4) {
        float zi[4], zf[4];
        #pragma unroll
        for (int q = 0; q < 4; ++q) {
            const size_t off = base + (size_t)(s0 + j + q) * 2048;
            zi[q] = zif[off]; zf[q] = zif[off + 1024];
        }
        #pragma unroll
        for (int q = 0; q < 4; ++q) {
            const float f  = sigf(zf[q]);
            const float ip = zi[q] * sigf(zi[q]) * (1.0f - f);
            L = fmaf(f, L, ip); P *= f;
        }
    }
    csum[(size_t)bh * NC + c] = make_float2(P, L);
}

// ---------------------------------------------------------------------------
// Recurrence pass 2: combine chunk prefixes, replay chunk, emit gh as bf16 hi/lo
// ---------------------------------------------------------------------------
__global__ __launch_bounds__(256) void scan2(
    const float* __restrict__ zif, const float* __restrict__ zg,
    const float2* __restrict__ csum,
    unsigned short* __restrict__ ghh, unsigned short* __restrict__ ghl)
{
    const int g  = blockIdx.x * 256 + threadIdx.x;
    const int c  = g >> 12;
    const int bh = g & 4095;
    const int b  = bh >> 10, h = bh & 1023;
    const size_t base  = (size_t)b * Ss * 2048 + h;   // zif
    const size_t baseg = (size_t)b * Ss * 1024 + h;   // zg / gh
    float hh = 0.0f;
    for (int cp = 0; cp < c; ++cp) {
        const float2 pl = csum[(size_t)bh * NC + cp];
        hh = fmaf(pl.x, hh, pl.y);
    }
    const int s0 = c * CL;
    for (int j = 0; j < CL; j += 4) {
        float zi[4], zf[4], gv[4];
        #pragma unroll
        for (int q = 0; q < 4; ++q) {
            const size_t off = base + (size_t)(s0 + j + q) * 2048;
            zi[q] = zif[off]; zf[q] = zif[off + 1024];
            gv[q] = zg[baseg + (size_t)(s0 + j + q) * 1024];
        }
        #pragma unroll
        for (int q = 0; q < 4; ++q) {
            const float f  = sigf(zf[q]);
            const float ip = zi[q] * sigf(zi[q]) * (1.0f - f);
            hh = fmaf(f, hh, ip);
            const float gh = gv[q] * hh;
            const unsigned short hi = f2bf(gh);
            const size_t off = baseg + (size_t)(s0 + j + q) * 1024;
            ghh[off] = hi;
            ghl[off] = f2bf(gh - bf2f(hi));
        }
    }
}

// ===========================================================================
// Round-1 fp32 fallback (only if ws_size is too small for the split path)
// ===========================================================================
__global__ __launch_bounds__(256) void proj_kernel(
    const float* __restrict__ x,  const float* __restrict__ Wi,
    const float* __restrict__ Wf, const float* __restrict__ Wg,
    float* __restrict__ f_out, float* __restrict__ inp_out, float* __restrict__ g_out)
{
    __shared__ __align__(16) float As [16][68];
    __shared__ __align__(16) float Bis[16][68];
    __shared__ __align__(16) float Bfs[16][68];
    __shared__ __align__(16) float Bgs[16][68];
    const int tid = threadIdx.x;
    const int tx = tid & 15, ty = tid >> 4;
    const int m0 = blockIdx.x * 64, n0 = blockIdx.y * 64;
    const int lr = tid >> 2, lk = (tid & 3) << 2;
    float acc_i[4][4] = {}, acc_f[4][4] = {}, acc_g[4][4] = {};
    const float* pA = x  + (size_t)(m0 + lr) * Hh + lk;
    const float* pI = Wi + (size_t)(n0 + lr) * Hh + lk;
    const float* pF = Wf + (size_t)(n0 + lr) * Hh + lk;
    const float* pG = Wg + (size_t)(n0 + lr) * Hh + lk;
    for (int k0 = 0; k0 < Hh; k0 += 16) {
        const float4 av = *(const float4*)(pA + k0);
        const float4 iv = *(const float4*)(pI + k0);
        const float4 fv = *(const float4*)(pF + k0);
        const float4 gv = *(const float4*)(pG + k0);
        __syncthreads();
        As [lk+0][lr] = av.x; As [lk+1][lr] = av.y; As [lk+2][lr] = av.z; As [lk+3][lr] = av.w;
        Bis[lk+0][lr] = iv.x; Bis[lk+1][lr] = iv.y; Bis[lk+2][lr] = iv.z; Bis[lk+3][lr] = iv.w;
        Bfs[lk+0][lr] = fv.x; Bfs[lk+1][lr] = fv.y; Bfs[lk+2][lr] = fv.z; Bfs[lk+3][lr] = fv.w;
        Bgs[lk+0][lr] = gv.x; Bgs[lk+1][lr] = gv.y; Bgs[lk+2][lr] = gv.z; Bgs[lk+3][lr] = gv.w;
        __syncthreads();
        #pragma unroll
        for (int kk = 0; kk < 16; ++kk) {
            const float4 a  = *(const float4*)&As [kk][ty << 2];
            const float4 bi = *(const float4*)&Bis[kk][tx << 2];
            const float4 bf = *(const float4*)&Bfs[kk][tx << 2];
            const float4 bg = *(const float4*)&Bgs[kk][tx << 2];
            const float aa[4]  = {a.x,a.y,a.z,a.w};
            const float bbi[4] = {bi.x,bi.y,bi.z,bi.w};
            const float bbf[4] = {bf.x,bf.y,bf.z,bf.w};
            const float bbg[4] = {bg.x,bg.y,bg.z,bg.w};
            #pragma unroll
            for (int i = 0; i < 4; ++i)
                #pragma unroll
                for (int j = 0; j < 4; ++j) {
                    acc_i[i][j] = fmaf(aa[i], bbi[j], acc_i[i][j]);
                    acc_f[i][j] = fmaf(aa[i], bbf[j], acc_f[i][j]);
                    acc_g[i][j] = fmaf(aa[i], bbg[j], acc_g[i][j]);
                }
        }
    }
    #pragma unroll
    for (int i = 0; i < 4; ++i) {
        const size_t row = (size_t)(m0 + (ty << 2) + i) * Hh + n0 + (tx << 2);
        float4 vf, vp, vg;
        float* qf = (float*)&vf; float* qp = (float*)&vp; float* qg = (float*)&vg;
        #pragma unroll
        for (int j = 0; j < 4; ++j) {
            const float ff = sigf(acc_f[i][j]);
            const float zi = acc_i[i][j];
            qf[j] = ff; qp[j] = zi * sigf(zi) * (1.0f - ff); qg[j] = acc_g[i][j];
        }
        *(float4*)(f_out + row) = vf;
        *(float4*)(inp_out + row) = vp;
        *(float4*)(g_out + row) = vg;
    }
}

__global__ __launch_bounds__(256) void recur_kernel(
    const float* f_buf, const float* __restrict__ inp_buf,
    const float* __restrict__ g_buf, float* gh_out)
{
    const int t = blockIdx.x * 256 + threadIdx.x;
    const int b = t >> 10, h = t & 1023;
    const size_t base = (size_t)b * Ss * Hh + h;
    float hh = 0.0f;
    for (int s0 = 0; s0 < Ss; s0 += 8) {
        float fr[8], ir[8], gr[8], o[8];
        #pragma unroll
        for (int j = 0; j < 8; ++j) {
            const size_t off = base + (size_t)(s0 + j) * Hh;
            fr[j] = f_buf[off]; ir[j] = inp_buf[off]; gr[j] = g_buf[off];
        }
        #pragma unroll
        for (int j = 0; j < 8; ++j) { hh = fmaf(fr[j], hh, ir[j]); o[j] = gr[j] * hh; }
        #pragma unroll
        for (int j = 0; j < 8; ++j) gh_out[base + (size_t)(s0 + j) * Hh] = o[j];
    }
}

__global__ __launch_bounds__(256) void out_kernel(
    const float* __restrict__ A, const float* __restrict__ Wo, float* __restrict__ out)
{
    __shared__ __align__(16) float As[16][68];
    __shared__ __align__(16) float Bs[16][68];
    const int tid = threadIdx.x;
    const int tx = tid & 15, ty = tid >> 4;
    const int m0 = blockIdx.x * 64, n0 = blockIdx.y * 64;
    const int lr = tid >> 2, lk = (tid & 3) << 2;
    float acc[4][4] = {};
    const float* pA = A  + (size_t)(m0 + lr) * Hh + lk;
    const float* pB = Wo + (size_t)(n0 + lr) * Hh + lk;
    for (int k0 = 0; k0 < Hh; k0 += 16) {
        const float4 av = *(const float4*)(pA + k0);
        const float4 bv = *(const float4*)(pB + k0);
        __syncthreads();
        As[lk+0][lr] = av.x; As[lk+1][lr] = av.y; As[lk+2][lr] = av.z; As[lk+3][lr] = av.w;
        Bs[lk+0][lr] = bv.x; Bs[lk+1][lr] = bv.y; Bs[lk+2][lr] = bv.z; Bs[lk+3][lr] = bv.w;
        __syncthreads();
        #pragma unroll
        for (int kk = 0; kk < 16; ++kk) {
            const float4 a = *(const float4*)&As[kk][ty << 2];
            const float4 b = *(const float4*)&Bs[kk][tx << 2];
            const float aa[4] = {a.x,a.y,a.z,a.w};
            const float bb[4] = {b.x,b.y,b.z,b.w};
            #pragma unroll
            for (int i = 0; i < 4; ++i)
                #pragma unroll
                for (int j = 0; j < 4; ++j)
                    acc[i][j] = fmaf(aa[i], bb[j], acc[i][j]);
        }
    }
    #pragma unroll
    for (int i = 0; i < 4; ++i) {
        const size_t row = (size_t)(m0 + (ty << 2) + i) * Hh + n0 + (tx << 2);
        float4 v;
        ((float*)&v)[0]=acc[i][0]; ((float*)&v)[1]=acc[i][1];
        ((float*)&v)[2]=acc[i][2]; ((float*)&v)[3]=acc[i][3];
        *(float4*)(out + row) = v;
    }
}

extern "C" void kernel_launch(void* const* d_in, const int* in_sizes, int n_in,
                              void* d_out, int out_size, void* d_ws, size_t ws_size,
                              hipStream_t stream) {
    const float* x  = (const float*)d_in[0];
    const float* Wi = (const float*)d_in[1];
    const float* Wf = (const float*)d_in[2];
    const float* Wg = (const float*)d_in[3];
    const float* Wo = (const float*)d_in[4];
    float* out = (float*)d_out;

    const size_t MH = (size_t)Mm * Hh;      // 8388608
    const size_t HH = (size_t)Hh * Hh;      // 1048576

    // ws layout (split path), ~152 MB:
    // xh[MH], xl[MH], Wallh[4HH], Walll[4HH] (rows: Wi,Wf,Wg,Wo),
    // zif[M*2048]f32, ghh[MH], ghl[MH], csum[4096*NC]float2
    size_t need = MH*2*2 + HH*4*2*2 + MH*2*4 + MH*2*2 + (size_t)4096*NC*8;

    if (ws_size >= need) {
        char* p = (char*)d_ws;
        unsigned short* xh    = (unsigned short*)p;  p += MH*2;
        unsigned short* xl    = (unsigned short*)p;  p += MH*2;
        unsigned short* Wallh = (unsigned short*)p;  p += HH*4*2;
        unsigned short* Walll = (unsigned short*)p;  p += HH*4*2;
        float* zif            = (float*)p;           p += MH*2*4;
        unsigned short* ghh   = (unsigned short*)p;  p += MH*2;
        unsigned short* ghl   = (unsigned short*)p;  p += MH*2;
        float2* csum          = (float2*)p;

        conv_split<<<(int)(MH/4/256), 256, 0, stream>>>(x, xh, xl, (int)(MH/4));
        conv_w4<<<dim3((unsigned)(HH/4/256/1), 4), 256, 0, stream>>>(Wi, Wf, Wg, Wo, Wallh, Walll);

        // fused projections: N=3072 (Wi|Wf|Wg); cols <2048 -> zif, >=2048 (z_g) -> d_out
        // tile 128x256: grid (3072/256, 8192/128)
        gemm_split<<<dim3(12, 64), 512, 0, stream>>>(
            xh, xl, Wallh, Walll, zif, 2048, out, 1024, 2048);

        scan1<<<512, 256, 0, stream>>>(zif, csum);
        scan2<<<512, 256, 0, stream>>>(zif, out, csum, ghh, ghl);

        // out = gh @ Wo^T  (Wo rows live at offset 3*HH in the concat)
        gemm_split<<<dim3(4, 64), 512, 0, stream>>>(
            ghh, ghl, Wallh + 3*HH, Walll + 3*HH, out, 1024, out, 1024, 1 << 30);
    } else {
        float* f_buf   = (float*)d_ws;
        float* inp_buf = f_buf + MH;
        dim3 grid(Mm / 64, Hh / 64);
        proj_kernel<<<grid, 256, 0, stream>>>(x, Wi, Wf, Wg, f_buf, inp_buf, out);
        recur_kernel<<<16, 256, 0, stream>>>(f_buf, inp_buf, out, f_buf);
        out_kernel<<<grid, 256, 0, stream>>>(f_buf, Wo, out);
    }
}